// Round 5
// baseline (14446.814 us; speedup 1.0000x reference)
//
#include <hip/hip_runtime.h>
#include <stdint.h>

// ComplexModel: 2-layer RNN(tanh) + 2-layer LSTM + FC on MI355X (gfx950)
// B=64 T=1024 D=256 H=256 HL=256 L=2 C=128
#define T_ 1024

typedef short bf16x8 __attribute__((ext_vector_type(8)));
typedef float f32x4  __attribute__((ext_vector_type(4)));
typedef int   i32x4  __attribute__((ext_vector_type(4)));
typedef unsigned short u16;

#define MFMA(a,b,c) __builtin_amdgcn_mfma_f32_16x16x32_bf16((a),(b),(c),0,0,0)

__device__ __forceinline__ u16 f2bf(float f){
  unsigned u = __float_as_uint(f);
  return (u16)((u + 0x7FFFu + ((u>>16)&1u)) >> 16);   // RNE
}
__device__ __forceinline__ float bf2f(u16 s){ return __uint_as_float(((unsigned)s)<<16); }
__device__ __forceinline__ float sigm(float x){ return 1.f/(1.f+__expf(-x)); }
__device__ __forceinline__ float tanhq(float x){ return 2.f/(1.f+__expf(-2.f*x)) - 1.f; }

__device__ __forceinline__ void gload16(const void* g, void* l){
  __builtin_amdgcn_global_load_lds(
      (const __attribute__((address_space(1))) unsigned int*)g,
      (__attribute__((address_space(3)))       unsigned int*)l, 16, 0, 0);
}
__device__ __forceinline__ void lgkm0_barrier(){
  asm volatile("s_waitcnt lgkmcnt(0)" ::: "memory");
  __builtin_amdgcn_s_barrier();
  asm volatile("" ::: "memory");
}

#define VMCNT(n) do{ asm volatile("s_waitcnt vmcnt(" #n ")" ::: "memory"); \
                     __builtin_amdgcn_sched_barrier(0); }while(0)
// coherent (LLC-visible, cache-bypass) ops
#define LD_X4C(dst,p)       asm volatile("global_load_dwordx4 %0, %1, off sc0 sc1" : "=v"(dst) : "v"(p) : "memory")
#define LD_DWC(dst,p)       asm volatile("global_load_dword %0, %1, off sc0 sc1" : "=v"(dst) : "v"(p) : "memory")
#define ST_U16C(p,v,OFF)    asm volatile("global_store_short %0, %1, off offset:" #OFF " sc0 sc1" :: "v"(p), "v"(v) : "memory")
#define ST_DWC(p,v)         asm volatile("global_store_dword %0, %1, off sc0 sc1" :: "v"(p), "v"(v) : "memory")
// normal cached ops (proj read / y,feat write cross dispatch boundaries)
#define LD_U16N(dst,p,OFF)  asm volatile("global_load_ushort %0, %1, off offset:" #OFF : "=v"(dst) : "v"(p) : "memory")
#define ST_U16N(p,v)        asm volatile("global_store_short %0, %1, off" :: "v"(p), "v"(v) : "memory")
#define ST_F32N(p,v,OFF)    asm volatile("global_store_dword %0, %1, off offset:" #OFF :: "v"(p), "v"(v) : "memory")

// ---------------- f32 -> bf16 conversion ----------------
__global__ void k_cvt(const float* __restrict__ s, u16* __restrict__ d, int n4){
  int i = blockIdx.x*blockDim.x + threadIdx.x;
  int stride = gridDim.x*blockDim.x;
  for (; i < n4; i += stride){
    float4 v = ((const float4*)s)[i];
    ushort4 o; o.x=f2bf(v.x); o.y=f2bf(v.y); o.z=f2bf(v.z); o.w=f2bf(v.w);
    ((ushort4*)d)[i] = o;
  }
}

// ---------------- bf16 GEMM: C[(t*64+b), N] = A[b*T+t][256] @ B[N,256]^T ----
__global__ __launch_bounds__(256,2) void k_gemm(
    const u16* __restrict__ A, const u16* __restrict__ Bm,
    u16* __restrict__ C, int N)
{
  __shared__ u16 As[128*64];
  __shared__ u16 Bs[128*64];
  const int tid = threadIdx.x;
  const int lane = tid & 63, w = tid >> 6;
  const int l15 = lane & 15, l4 = lane >> 4;
  const long m0 = (long)blockIdx.x * 128;
  const int  n0 = blockIdx.y * 128;
  const int  mo = (w>>1)*64, no = (w&1)*64;

  f32x4 acc[4][4];
  #pragma unroll
  for (int i=0;i<4;++i)
    #pragma unroll
    for (int j=0;j<4;++j) acc[i][j] = (f32x4){0.f,0.f,0.f,0.f};

  for (int kt=0; kt<4; ++kt){
    const int k0 = kt*64;
    #pragma unroll
    for (int i=0;i<4;++i){
      int fb = (i*256+tid)*16;
      int r  = fb>>7, cbyte = fb&127;
      gload16(A + (m0 + r)*256 + k0 + (cbyte>>1), (char*)As + fb);
      gload16(Bm + (long)(n0 + r)*256 + k0 + (cbyte>>1), (char*)Bs + fb);
    }
    __syncthreads();
    #pragma unroll
    for (int kb=0;kb<2;++kb){
      bf16x8 a[4], b[4];
      #pragma unroll
      for (int mb=0;mb<4;++mb)
        a[mb] = *(const bf16x8*)(As + (mo+mb*16+l15)*64 + kb*32 + l4*8);
      #pragma unroll
      for (int nb=0;nb<4;++nb)
        b[nb] = *(const bf16x8*)(Bs + (no+nb*16+l15)*64 + kb*32 + l4*8);
      #pragma unroll
      for (int mb=0;mb<4;++mb)
        #pragma unroll
        for (int nb=0;nb<4;++nb)
          acc[mb][nb] = MFMA(a[mb], b[nb], acc[mb][nb]);
    }
    __syncthreads();
  }
  #pragma unroll
  for (int mb=0;mb<4;++mb)
    #pragma unroll
    for (int nb=0;nb<4;++nb)
      #pragma unroll
      for (int j=0;j<4;++j){
        long m   = m0 + mo + mb*16 + l4*4 + j;       // m = b*1024 + t
        long crow= (long)(m & 1023)*64 + (m >> 10);  // -> t*64 + b
        int  col = n0 + no + nb*16 + l15;
        C[crow*N + col] = f2bf(acc[mb][nb][j]);
      }
}

// ---------------- fused recurrence kernel ----------------
// blocks 0..3 : RNN, batch-split (16 rows), Whh(hi/lo) in regs, h in LDS.
// blocks 4..11: LSTM, 8 slices x 32 units; 4 batch-chains round-robin;
//               plain-bf16 h exchange + per-wave flag release (no fences),
//               3-slot-ahead issue, uniform 19 VMEM/slot counted vmcnt.
__global__ __launch_bounds__(512,2) void k_rec(
    const u16*  __restrict__ projR,  // [t*64+b][256] bf16
    const float* __restrict__ WhhR,
    const float* __restrict__ bihR, const float* __restrict__ bhhR,
    u16* __restrict__ yR,            // [b*T+t][256] bf16 or null
    const u16*  __restrict__ projL,  // [t*64+b][1024] bf16
    const float* __restrict__ WhhL,
    const float* __restrict__ bihL, const float* __restrict__ bhhL,
    u16* __restrict__ yL,            // [b*T+t][256] bf16
    u16* __restrict__ hbuf,          // bf16 [2][64][256] LSTM h exchange
    int* __restrict__ flags,         // [4 chain][64 producer-wave] step counters
    float* __restrict__ feat,        // [64][512] f32 (dummy for layer1)
    int isLast)
{
  __shared__ u16 hlds[16*256];       // RNN h
  __shared__ u16 lsm[2*16*256];      // LSTM staged h (E/O x 8KB)
  const int tid = threadIdx.x;
  const int lane = tid & 63, w = tid >> 6;
  const int l15 = lane & 15, l4 = lane >> 4;
  const int bid = blockIdx.x;

  if (bid < 4){
    // =============== RNN (proven; unchanged) ===============
    const int g = bid;
    const int cb = 32*w;
    bf16x8 bhi[2][8], blo[2][8];
    #pragma unroll
    for (int nb=0;nb<2;++nb){
      const int col = cb + nb*16 + l15;
      #pragma unroll
      for (int kb=0;kb<8;++kb){
        const float* wp = WhhR + (long)col*256 + kb*32 + l4*8;
        #pragma unroll
        for (int j=0;j<8;++j){
          float wv = wp[j];
          u16 hi = f2bf(wv);
          bhi[nb][kb][j] = (short)hi;
          blo[nb][kb][j] = (short)f2bf(wv - bf2f(hi));
        }
      }
    }
    float bias[2];
    #pragma unroll
    for (int nb=0;nb<2;++nb){ int col = cb+nb*16+l15; bias[nb]=bihR[col]+bhhR[col]; }

    u16 pfr[8];
    #pragma unroll
    for (int nb=0;nb<2;++nb)
      #pragma unroll
      for (int j=0;j<4;++j)
        pfr[nb*4+j] = projR[(long)(16*g + l4*4 + j)*256 + cb + nb*16 + l15];

    for (int t=0; t<T_; ++t){
      lgkm0_barrier();
      f32x4 acc0 = {0.f,0.f,0.f,0.f}, acc1 = acc0;
      if (t > 0){
        bf16x8 a[8];
        #pragma unroll
        for (int kb=0;kb<8;++kb){
          int bo = (l15*512 + kb*64 + l4*16) ^ ((l15&7)<<4);
          a[kb] = *(const bf16x8*)((const char*)hlds + bo);
        }
        #pragma unroll
        for (int kb=0;kb<8;++kb){
          acc0 = MFMA(a[kb], bhi[0][kb], acc0);
          acc0 = MFMA(a[kb], blo[0][kb], acc0);
          acc1 = MFMA(a[kb], bhi[1][kb], acc1);
          acc1 = MFMA(a[kb], blo[1][kb], acc1);
        }
      }
      float hv[2][4];
      #pragma unroll
      for (int nb=0;nb<2;++nb)
        #pragma unroll
        for (int j=0;j<4;++j){
          float pre = (nb ? acc1[j] : acc0[j]) + bf2f(pfr[nb*4+j]) + bias[nb];
          hv[nb][j] = tanhq(pre);
        }
      int tn = (t+1 < T_) ? t+1 : t;
      #pragma unroll
      for (int nb=0;nb<2;++nb)
        #pragma unroll
        for (int j=0;j<4;++j)
          pfr[nb*4+j] = projR[(long)(tn*64 + 16*g + l4*4 + j)*256 + cb + nb*16 + l15];
      lgkm0_barrier();
      #pragma unroll
      for (int nb=0;nb<2;++nb)
        #pragma unroll
        for (int j=0;j<4;++j){
          int m = l4*4 + j, u = cb + nb*16 + l15;
          u16 hb = f2bf(hv[nb][j]);
          int bo = (m*512 + u*2) ^ ((m&7)<<4);
          *(u16*)((char*)hlds + bo) = hb;
          if (yR) yR[((long)(16*g+m)*T_ + t)*256 + u] = hb;
          if (isLast && t == T_-1) feat[(16*g+m)*512 + u] = hv[nb][j];
        }
    }
  } else {
    // =============== LSTM: 8 WGs x 32 units, flag-release protocol ===============
    const int hg = bid - 4;
    const int g_  = l15 & 3;                // lane's gate (i,f,g,o)
    const int u_  = 32*hg + 4*w + (l15>>2); // lane's unit
    const bool gl0 = (g_ == 0);
    const bool isG = (g_ == 2);
    const int wgw = hg*8 + w;               // producer-wave flag index
    const int srow = tid >> 5;              // staged LDS row this lane fills
    const int swro = ((srow*512 + (tid&31)*16) ^ ((srow&7)<<4));
    char* lsmBE = (char*)lsm;
    char* lsmBO = (char*)lsm + 8192;

    // weights (hi/lo) + bias for this lane's gate-row
    bf16x8 bhi[8], blo[8];
    const long wrow = (long)(g_*256 + u_);
    const float bias0 = bihL[wrow] + bhhL[wrow];
    #pragma unroll
    for (int kb=0;kb<8;++kb){
      const float* wp = WhhL + wrow*256 + kb*32 + l4*8;
      #pragma unroll
      for (int j=0;j<8;++j){
        float wv = wp[j];
        u16 hi = f2bf(wv);
        bhi[kb][j] = (short)hi;
        blo[kb][j] = (short)f2bf(wv - bf2f(hi));
      }
    }
    float cst[4][4];
    #pragma unroll
    for (int b_=0;b_<4;++b_){ cst[b_][0]=0.f;cst[b_][1]=0.f;cst[b_][2]=0.f;cst[b_][3]=0.f; }
    i32x4 f0, f1, f2, f3;
    unsigned pf0[4], pf1[4], pf2[4], pf3[4];
    int pVal = 0, pTgt = 0;
    const int* pAddr = flags + lane;

    #define PFR4(PF, TT, CC) do{                                               \
      const u16* pb  = projL + (size_t)((TT)*64 + 16*(CC) + l4*4)*1024 + g_*256 + u_; \
      const u16* pb2 = pb + 2048;                                              \
      LD_U16N(PF[0], pb, 0);  LD_U16N(PF[1], pb, 2048);                        \
      LD_U16N(PF[2], pb2, 0); LD_U16N(PF[3], pb2, 2048);                       \
    }while(0)

    // act + 12 stores (4 slab sc + 4 y + 4 feat). cst valid on gl0 lanes only.
    #define LACT(CC, A0, PF, TT) do{                                           \
      float hcur[4];                                                           \
      _Pragma("unroll")                                                        \
      for (int j=0;j<4;++j){                                                   \
        float sv = A0[j] + bf2f((u16)PF[j]) + bias0;                           \
        float av = isG ? tanhq(sv) : sigm(sv);                                 \
        float x1 = __shfl_xor(av,1);                                           \
        float x2 = __shfl_xor(av,2);                                           \
        float x3 = __shfl_xor(av,3);                                           \
        float cv = x1*cst[CC][j] + av*x2;                                      \
        cst[CC][j] = cv;                                                       \
        hcur[j] = x3 * tanhq(cv);                                              \
      }                                                                        \
      if (gl0){                                                                \
        u16* hb = hbuf + (size_t)(((TT)+1)&1)*16384 + (size_t)(16*(CC) + l4*4)*256 + u_; \
        unsigned h0=f2bf(hcur[0]), h1=f2bf(hcur[1]), h2=f2bf(hcur[2]), h3=f2bf(hcur[3]); \
        ST_U16C(hb, h0, 0); ST_U16C(hb, h1, 512);                              \
        ST_U16C(hb, h2, 1024); ST_U16C(hb, h3, 1536);                          \
        u16* yb = yL + ((size_t)(16*(CC) + l4*4)*T_ + (TT))*256 + u_;          \
        ST_U16N(yb, h0); yb += (size_t)T_*256;                                 \
        ST_U16N(yb, h1); yb += (size_t)T_*256;                                 \
        ST_U16N(yb, h2); yb += (size_t)T_*256;                                 \
        ST_U16N(yb, h3);                                                       \
        float* fb  = feat + (size_t)(16*(CC) + l4*4)*512 + 256 + u_;           \
        float* fb2 = fb + 1024;                                                \
        ST_F32N(fb, hcur[0], 0); ST_F32N(fb, hcur[1], 2048);                   \
        ST_F32N(fb2, hcur[2], 0); ST_F32N(fb2, hcur[3], 2048);                 \
      }                                                                        \
    }while(0)

    // ---- prologue t=0 (h_0 = c_0 = 0) ----
    f32x4 zacc = {0.f,0.f,0.f,0.f};
    #define LPRO(CC, PF) do{                                                   \
      PFR4(PF, 0, CC); VMCNT(0);                                               \
      LACT(CC, zacc, PF, 0);                                                   \
      VMCNT(0);                                                                \
      { int fv = 1; if (lane == 0) ST_DWC(flags + (CC)*64 + wgw, fv); }        \
    }while(0)
    LPRO(0, pf0); LPRO(1, pf1); LPRO(2, pf2); LPRO(3, pf3);

    // ---- prime frags for chains 0,1 at t=1 ----
    #define PRIME(CC, FR, PF) do{                                              \
      const int* pa = flags + (CC)*64 + lane;                                  \
      LD_DWC(pVal, pa); VMCNT(0);                                              \
      while (!__all(pVal >= 1)){ __builtin_amdgcn_s_sleep(2);                  \
        LD_DWC(pVal, pa); VMCNT(0); }                                          \
      const u16* fp = hbuf + 16384 + (size_t)(16*(CC) + srow)*256 + (tid&31)*8; \
      LD_X4C(FR, fp);                                                          \
      PFR4(PF, 1, CC);                                                         \
    }while(0)
    PRIME(0, f0, pf0);
    PRIME(1, f1, pf1);
    pAddr = flags + 2*64 + lane; pTgt = 1;
    LD_DWC(pVal, pAddr);

    // ---- steady slots: 19 VMEM/slot, counted waits ----
    #define LSLOT(CC, FCUR, FNXT, PFCUR, PFNXT, LSB, W1N, W2N) do{             \
      VMCNT(W1N);                          /* FCUR retired */                  \
      *(i32x4*)(lsmB##LSB + swro) = FCUR;                                      \
      asm volatile("s_waitcnt lgkmcnt(0)" ::: "memory");                       \
      __builtin_amdgcn_s_barrier();                                            \
      __builtin_amdgcn_sched_barrier(0);                                       \
      f32x4 acc = {0.f,0.f,0.f,0.f};                                           \
      _Pragma("unroll")                                                        \
      for (int kb=0;kb<8;++kb){                                                \
        bf16x8 a = *(const bf16x8*)(lsmB##LSB + ((l15*512 + kb*64 + l4*16) ^ ((l15&7)<<4))); \
        acc = MFMA(a, bhi[kb], acc);                                           \
        acc = MFMA(a, blo[kb], acc);                                           \
      }                                                                        \
      VMCNT(W2N);                          /* PFCUR retired */                 \
      LACT(CC, acc, PFCUR, t);                                                 \
      VMCNT(8);                            /* slab retired (y/feat float) */   \
      { int fv = t+1; if (lane == 0) ST_DWC(flags + (CC)*64 + wgw, fv); }      \
      VMCNT(13);                           /* poll value readable */           \
      while (!__all(pVal >= pTgt)){ __builtin_amdgcn_s_sleep(2);               \
        LD_DWC(pVal, pAddr); VMCNT(0); }                                       \
      { const int nc = ((CC)+2)&3;                                             \
        int tn = ((CC)<2) ? t : t+1; if (tn > T_-1) tn = T_-1;                 \
        const u16* fp = hbuf + (size_t)(tn&1)*16384 + (size_t)(16*nc + srow)*256 + (tid&31)*8; \
        LD_X4C(FNXT, fp);                                                      \
        PFR4(PFNXT, tn, nc);                                                   \
        const int nc2 = ((CC)+3)&3;                                            \
        int tn2 = ((CC)==0) ? t : t+1; if (tn2 > T_-1) tn2 = T_-1;             \
        pAddr = flags + nc2*64 + lane; pTgt = tn2;                             \
        LD_DWC(pVal, pAddr); }                                                 \
    }while(0)

    {
      int t = 1;
      LSLOT(0, f0, f2, pf0, pf2, E, 6, 6);     // first steady slot: prime counts
      LSLOT(1, f1, f3, pf1, pf3, O, 24, 20);
      LSLOT(2, f2, f0, pf2, pf0, E, 24, 20);
      LSLOT(3, f3, f1, pf3, pf1, O, 24, 20);
    }
    for (int t=2; t<T_; ++t){
      LSLOT(0, f0, f2, pf0, pf2, E, 24, 20);
      LSLOT(1, f1, f3, pf1, pf3, O, 24, 20);
      LSLOT(2, f2, f0, pf2, pf0, E, 24, 20);
      LSLOT(3, f3, f1, pf3, pf1, O, 24, 20);
    }
    VMCNT(0);
  }
}

// ---------------- FC ----------------
__global__ void k_fc(const float* __restrict__ feat, const float* __restrict__ W,
                     const float* __restrict__ bias, float* __restrict__ out){
  int o = blockIdx.x*blockDim.x + threadIdx.x;
  if (o >= 64*128) return;
  int b = o >> 7, c = o & 127;
  float s = bias[c];
  const float* f  = feat + b*512;
  const float* wr = W + c*512;
  #pragma unroll 8
  for (int k=0;k<512;++k) s += f[k]*wr[k];
  out[o] = s;
}

extern "C" void kernel_launch(void* const* d_in, const int* in_sizes, int n_in,
                              void* d_out, int out_size, void* d_ws, size_t ws_size,
                              hipStream_t stream)
{
  (void)in_sizes; (void)n_in; (void)out_size; (void)ws_size;
  const float* rnn_x    = (const float*)d_in[0];
  const float* lstm_x   = (const float*)d_in[1];
  const float* rnn_Wih  = (const float*)d_in[2];
  const float* rnn_Whh  = (const float*)d_in[3];
  const float* rnn_bih  = (const float*)d_in[4];
  const float* rnn_bhh  = (const float*)d_in[5];
  const float* lstm_Wih = (const float*)d_in[6];
  const float* lstm_Whh = (const float*)d_in[7];
  const float* lstm_bih = (const float*)d_in[8];
  const float* lstm_bhh = (const float*)d_in[9];
  const float* fc_W     = (const float*)d_in[10];
  const float* fc_b     = (const float*)d_in[11];
  float* out = (float*)d_out;

  char* ws = (char*)d_ws; size_t off = 0;
  auto alloc = [&](size_t b)->char*{ char* p = ws + off; off += (b + 255) & ~(size_t)255; return p; };
  const size_t NE = (size_t)64*1024*256;
  u16*  wih_r = (u16*)alloc(2*256*256*2);
  u16*  wih_l = (u16*)alloc(2*1024*256*2);
  u16*  xr    = (u16*)alloc(NE*2);                 // rnn_x bf16 -> later y1R
  u16*  xl    = (u16*)alloc(NE*2);                 // lstm_x bf16 -> later y1L -> L2 dump
  u16*  projR = (u16*)alloc(NE*2);
  u16*  projL = (u16*)alloc(NE*4*2);
  u16*  hbuf  = (u16*)alloc(2*64*256*2);           // plain bf16 h exchange
  int*  flag1 = (int*)alloc(4*64*4);               // layer-1 flags
  int*  flag2 = (int*)alloc(4*64*4);               // layer-2 flags
  float* featD = (float*)alloc(64*512*4);          // dummy feat (layer1)
  float* feat  = (float*)alloc(64*512*4);

  hipMemsetAsync(flag1, 0, 2*4*64*4, stream);      // covers flag1+flag2 (contiguous)
  k_cvt<<<2048,256,0,stream>>>(rnn_x,  xr, (int)(NE/4));
  k_cvt<<<2048,256,0,stream>>>(lstm_x, xl, (int)(NE/4));
  k_cvt<<<64, 256,0,stream>>>(rnn_Wih,  wih_r, 2*256*256/4);
  k_cvt<<<256,256,0,stream>>>(lstm_Wih, wih_l, 2*1024*256/4);
  k_gemm<<<dim3(512,2),256,0,stream>>>(xr, wih_r, projR, 256);
  k_gemm<<<dim3(512,8),256,0,stream>>>(xl, wih_l, projL, 1024);
  k_rec<<<12,512,0,stream>>>(projR, rnn_Whh, rnn_bih, rnn_bhh, xr,
                             projL, lstm_Whh, lstm_bih, lstm_bhh, xl,
                             hbuf, flag1, featD, 0);
  k_gemm<<<dim3(512,2),256,0,stream>>>(xr, wih_r + 256*256,  projR, 256);
  k_gemm<<<dim3(512,8),256,0,stream>>>(xl, wih_l + 1024*256, projL, 1024);
  // layer-2: yL written into xl (dead) to keep VMEM counts uniform
  k_rec<<<12,512,0,stream>>>(projR, rnn_Whh + 256*256, rnn_bih + 256, rnn_bhh + 256, nullptr,
                             projL, lstm_Whh + 1024*256, lstm_bih + 1024, lstm_bhh + 1024, xl,
                             hbuf, flag2, feat, 1);
  k_fc<<<32,256,0,stream>>>(feat, fc_W, fc_b, out);
}